// Round 1
// baseline (391.804 us; speedup 1.0000x reference)
//
#include <hip/hip_runtime.h>
#include <math.h>

#define NN 50000
#define NE 1000000
#define FIN 128
#define FOUT 64
#define NEG 0.2f

// Kernel 1: Wh = x @ W  [N,64], plus fused s_src = Wh·a_src, s_dst = Wh·a_dst.
// Layout: lane = output feature (FOUT=64 = one wave). Each wave processes 4
// consecutive nodes per iteration to amortize the LDS read of W.
// x row accesses are wave-uniform (readfirstlane) -> scalar s_load path.
__global__ __launch_bounds__(256) void k_gemm(
    const float* __restrict__ x, const float* __restrict__ W,
    const float* __restrict__ a_src, const float* __restrict__ a_dst,
    float* __restrict__ Wh, float* __restrict__ s_src, float* __restrict__ s_dst)
{
    __shared__ float Wl[FIN * FOUT];   // 32 KB
    for (int i = threadIdx.x; i < FIN * FOUT; i += 256) Wl[i] = W[i];
    __syncthreads();

    const int lane = threadIdx.x & 63;
    const int wave = threadIdx.x >> 6;
    const float asv = a_src[lane];
    const float adv = a_dst[lane];

    const int ngroups = NN / 4;        // 12500, exact
    for (int g = blockIdx.x * 4 + wave; g < ngroups; g += gridDim.x * 4) {
        const int gu = __builtin_amdgcn_readfirstlane(g);
        const float* xr = x + (size_t)gu * (4 * FIN);
        float a0 = 0.f, a1 = 0.f, a2 = 0.f, a3 = 0.f;
        #pragma unroll 8
        for (int k = 0; k < FIN; ++k) {
            const float wv = Wl[k * FOUT + lane];
            a0 = fmaf(xr[k],           wv, a0);
            a1 = fmaf(xr[FIN + k],     wv, a1);
            a2 = fmaf(xr[2 * FIN + k], wv, a2);
            a3 = fmaf(xr[3 * FIN + k], wv, a3);
        }
        const int n0 = gu * 4;
        Wh[(size_t)n0 * FOUT + lane]       = a0;
        Wh[(size_t)(n0 + 1) * FOUT + lane] = a1;
        Wh[(size_t)(n0 + 2) * FOUT + lane] = a2;
        Wh[(size_t)(n0 + 3) * FOUT + lane] = a3;

        float r0s = a0 * asv, r0d = a0 * adv;
        float r1s = a1 * asv, r1d = a1 * adv;
        float r2s = a2 * asv, r2d = a2 * adv;
        float r3s = a3 * asv, r3d = a3 * adv;
        #pragma unroll
        for (int off = 32; off; off >>= 1) {
            r0s += __shfl_xor(r0s, off); r0d += __shfl_xor(r0d, off);
            r1s += __shfl_xor(r1s, off); r1d += __shfl_xor(r1d, off);
            r2s += __shfl_xor(r2s, off); r2d += __shfl_xor(r2d, off);
            r3s += __shfl_xor(r3s, off); r3d += __shfl_xor(r3d, off);
        }
        if (lane == 0) {
            s_src[n0]     = r0s; s_dst[n0]     = r0d;
            s_src[n0 + 1] = r1s; s_dst[n0 + 1] = r1d;
            s_src[n0 + 2] = r2s; s_dst[n0 + 2] = r2d;
            s_src[n0 + 3] = r3s; s_dst[n0 + 3] = r3d;
        }
    }
}

// Kernel 2: per-edge logits. NOTE: the reference's global-max stabilizer
// cancels exactly in alpha = e/denom; logits are bounded (~30) so raw exp is
// safe in fp32. e_vals[e] = exp(lrelu(...)); denom[dst] += e_vals[e].
__global__ __launch_bounds__(256) void k_edge_e(
    const int* __restrict__ ei, const float* __restrict__ s_src,
    const float* __restrict__ s_dst, float* __restrict__ e_vals,
    float* __restrict__ denom)
{
    const int e = blockIdx.x * 256 + threadIdx.x;
    if (e >= NE) return;
    const int s = ei[e];
    const int d = ei[NE + e];
    float v = s_src[s] + s_dst[d];
    v = (v > 0.f) ? v : NEG * v;
    const float ev = __expf(v);
    e_vals[e] = ev;
    atomicAdd(&denom[d], ev);
}

// Kernel 3: scatter-accumulate. One wave per edge, lane = feature.
// out[dst][f] += Wh[src][f] * (e / (denom[dst] + 1e-16)).
__global__ __launch_bounds__(256) void k_scatter(
    const int* __restrict__ ei, const float* __restrict__ e_vals,
    const float* __restrict__ denom, const float* __restrict__ Wh,
    float* __restrict__ out)
{
    const long long gid = (long long)blockIdx.x * 256 + threadIdx.x;
    const int e = (int)(gid >> 6);
    if (e >= NE) return;
    const int lane = threadIdx.x & 63;
    const int s = ei[e];
    const int d = ei[NE + e];
    const float alpha = e_vals[e] / (denom[d] + 1e-16f);
    const float w = Wh[(size_t)s * FOUT + lane];
    atomicAdd(&out[(size_t)d * FOUT + lane], w * alpha);
}

// Kernel 4: in-place ELU epilogue.
__global__ __launch_bounds__(256) void k_elu(float* __restrict__ out)
{
    const int i = blockIdx.x * 256 + threadIdx.x;
    if (i < NN * FOUT) {
        const float v = out[i];
        out[i] = (v > 0.f) ? v : expm1f(v);
    }
}

extern "C" void kernel_launch(void* const* d_in, const int* in_sizes, int n_in,
                              void* d_out, int out_size, void* d_ws, size_t ws_size,
                              hipStream_t stream)
{
    const float* x     = (const float*)d_in[0];
    const int*   ei    = (const int*)d_in[1];   // [2,E] flat: src = ei[0..E), dst = ei[E..2E)
    const float* W     = (const float*)d_in[2];
    const float* a_src = (const float*)d_in[3];
    const float* a_dst = (const float*)d_in[4];
    float* out = (float*)d_out;

    // Workspace layout (floats): Wh[N*64] | s_src[N] | s_dst[N] | e_vals[E] | denom[N]
    float* ws     = (float*)d_ws;
    float* Wh     = ws;
    float* s_src  = Wh + (size_t)NN * FOUT;
    float* s_dst  = s_src + NN;
    float* e_vals = s_dst + NN;
    float* denom  = e_vals + NE;

    hipMemsetAsync(denom, 0, NN * sizeof(float), stream);
    hipMemsetAsync(out, 0, (size_t)NN * FOUT * sizeof(float), stream);

    k_gemm<<<1024, 256, 0, stream>>>(x, W, a_src, a_dst, Wh, s_src, s_dst);
    k_edge_e<<<(NE + 255) / 256, 256, 0, stream>>>(ei, s_src, s_dst, e_vals, denom);
    k_scatter<<<(NE * 64) / 256, 256, 0, stream>>>(ei, e_vals, denom, Wh, out);
    k_elu<<<(NN * FOUT + 255) / 256, 256, 0, stream>>>(out);
}

// Round 2
// 261.907 us; speedup vs baseline: 1.4960x; 1.4960x over previous
//
#include <hip/hip_runtime.h>
#include <math.h>

#define NN 50000
#define NE 1000000
#define FIN 128
#define FOUT 64
#define NEG 0.2f

// Kernel 1: Wh = x @ W  [N,64], fused s_src = Wh·a_src, s_dst = Wh·a_dst.
// lane = output feature; 4 nodes per wave-iteration; x row loads are
// wave-uniform (scalar path), W staged in LDS.
__global__ __launch_bounds__(256) void k_gemm(
    const float* __restrict__ x, const float* __restrict__ W,
    const float* __restrict__ a_src, const float* __restrict__ a_dst,
    float* __restrict__ Wh, float* __restrict__ s_src, float* __restrict__ s_dst)
{
    __shared__ float Wl[FIN * FOUT];   // 32 KB
    for (int i = threadIdx.x; i < FIN * FOUT; i += 256) Wl[i] = W[i];
    __syncthreads();

    const int lane = threadIdx.x & 63;
    const int wave = threadIdx.x >> 6;
    const float asv = a_src[lane];
    const float adv = a_dst[lane];

    const int ngroups = NN / 4;        // 12500, exact
    for (int g = blockIdx.x * 4 + wave; g < ngroups; g += gridDim.x * 4) {
        const int gu = __builtin_amdgcn_readfirstlane(g);
        const float* xr = x + (size_t)gu * (4 * FIN);
        float a0 = 0.f, a1 = 0.f, a2 = 0.f, a3 = 0.f;
        #pragma unroll 8
        for (int k = 0; k < FIN; ++k) {
            const float wv = Wl[k * FOUT + lane];
            a0 = fmaf(xr[k],           wv, a0);
            a1 = fmaf(xr[FIN + k],     wv, a1);
            a2 = fmaf(xr[2 * FIN + k], wv, a2);
            a3 = fmaf(xr[3 * FIN + k], wv, a3);
        }
        const int n0 = gu * 4;
        Wh[(size_t)n0 * FOUT + lane]       = a0;
        Wh[(size_t)(n0 + 1) * FOUT + lane] = a1;
        Wh[(size_t)(n0 + 2) * FOUT + lane] = a2;
        Wh[(size_t)(n0 + 3) * FOUT + lane] = a3;

        float r0s = a0 * asv, r0d = a0 * adv;
        float r1s = a1 * asv, r1d = a1 * adv;
        float r2s = a2 * asv, r2d = a2 * adv;
        float r3s = a3 * asv, r3d = a3 * adv;
        #pragma unroll
        for (int off = 32; off; off >>= 1) {
            r0s += __shfl_xor(r0s, off); r0d += __shfl_xor(r0d, off);
            r1s += __shfl_xor(r1s, off); r1d += __shfl_xor(r1d, off);
            r2s += __shfl_xor(r2s, off); r2d += __shfl_xor(r2d, off);
            r3s += __shfl_xor(r3s, off); r3d += __shfl_xor(r3d, off);
        }
        if (lane == 0) {
            s_src[n0]     = r0s; s_dst[n0]     = r0d;
            s_src[n0 + 1] = r1s; s_dst[n0 + 1] = r1d;
            s_src[n0 + 2] = r2s; s_dst[n0 + 2] = r2d;
            s_src[n0 + 3] = r3s; s_dst[n0 + 3] = r3d;
        }
    }
}

// Kernel 2: in-degree histogram.
__global__ __launch_bounds__(256) void k_hist(
    const int* __restrict__ ei, int* __restrict__ counts)
{
    const int e = blockIdx.x * 256 + threadIdx.x;
    if (e < NE) atomicAdd(&counts[ei[NE + e]], 1);
}

// Kernel 3: single-block exclusive scan of counts[0..NN) -> offsets[0..NN],
// duplicate into cursor[]. 1024 threads, 8 items/thread/iter.
__global__ __launch_bounds__(1024) void k_scan(
    const int* __restrict__ counts, int* __restrict__ offsets,
    int* __restrict__ cursor)
{
    __shared__ int wsum[16];
    const int tid = threadIdx.x;
    const int lane = tid & 63;
    const int wv = tid >> 6;
    int running = 0;

    for (int base = 0; base < NN; base += 1024 * 8) {
        const int i0 = base + tid * 8;
        int v[8];
        int s = 0;
        #pragma unroll
        for (int j = 0; j < 8; ++j) {
            const int idx = i0 + j;
            v[j] = (idx < NN) ? counts[idx] : 0;
            s += v[j];
        }
        // wave-inclusive scan of s
        int sc = s;
        #pragma unroll
        for (int off = 1; off < 64; off <<= 1) {
            const int t = __shfl_up(sc, off);
            if (lane >= off) sc += t;
        }
        if (lane == 63) wsum[wv] = sc;
        __syncthreads();
        if (wv == 0 && lane < 16) {
            int w = wsum[lane];
            #pragma unroll
            for (int off = 1; off < 16; off <<= 1) {
                const int t = __shfl_up(w, off);
                if (lane >= off) w += t;
            }
            wsum[lane] = w;
        }
        __syncthreads();
        const int block_prefix = (wv > 0) ? wsum[wv - 1] : 0;
        int excl = running + block_prefix + (sc - s);
        #pragma unroll
        for (int j = 0; j < 8; ++j) {
            const int idx = i0 + j;
            if (idx < NN) { offsets[idx] = excl; cursor[idx] = excl; }
            excl += v[j];
        }
        const int total = wsum[15];
        __syncthreads();
        running += total;
    }
    if (tid == 0) offsets[NN] = running;   // == NE
}

// Kernel 4: per-edge ev + CSR fill (slot allocation via cursor atomics).
// Global-max stabilizer cancels in alpha = e/denom; logits bounded -> raw exp.
__global__ __launch_bounds__(256) void k_fill(
    const int* __restrict__ ei, const float* __restrict__ s_src,
    const float* __restrict__ s_dst, int* __restrict__ cursor,
    int* __restrict__ csr_src, float* __restrict__ csr_ev)
{
    const int e = blockIdx.x * 256 + threadIdx.x;
    if (e >= NE) return;
    const int s = ei[e];
    const int d = ei[NE + e];
    float v = s_src[s] + s_dst[d];
    v = (v > 0.f) ? v : NEG * v;
    const float ev = __expf(v);
    const int pos = atomicAdd(&cursor[d], 1);
    csr_src[pos] = s;
    csr_ev[pos]  = ev;
}

// Kernel 5: gather per dst node. One wave per node, lane = feature.
// Fuses denom accumulation, normalization, and ELU. No atomics.
__global__ __launch_bounds__(256) void k_gather(
    const int* __restrict__ offsets, const int* __restrict__ csr_src,
    const float* __restrict__ csr_ev, const float* __restrict__ Wh,
    float* __restrict__ out)
{
    const int n = blockIdx.x * 4 + (threadIdx.x >> 6);   // 12500 blocks -> exact
    const int lane = threadIdx.x & 63;
    const int beg = offsets[n];
    const int end = offsets[n + 1];

    float acc = 0.f, den = 0.f;
    int i = beg;
    for (; i + 4 <= end; i += 4) {
        const int s0 = csr_src[i];
        const int s1 = csr_src[i + 1];
        const int s2 = csr_src[i + 2];
        const int s3 = csr_src[i + 3];
        const float e0 = csr_ev[i];
        const float e1 = csr_ev[i + 1];
        const float e2 = csr_ev[i + 2];
        const float e3 = csr_ev[i + 3];
        acc = fmaf(e0, Wh[(size_t)s0 * FOUT + lane], acc);
        acc = fmaf(e1, Wh[(size_t)s1 * FOUT + lane], acc);
        acc = fmaf(e2, Wh[(size_t)s2 * FOUT + lane], acc);
        acc = fmaf(e3, Wh[(size_t)s3 * FOUT + lane], acc);
        den += (e0 + e1) + (e2 + e3);
    }
    for (; i < end; ++i) {
        const int s0 = csr_src[i];
        const float e0 = csr_ev[i];
        acc = fmaf(e0, Wh[(size_t)s0 * FOUT + lane], acc);
        den += e0;
    }
    const float r = acc / (den + 1e-16f);
    out[(size_t)n * FOUT + lane] = (r > 0.f) ? r : expm1f(r);
}

extern "C" void kernel_launch(void* const* d_in, const int* in_sizes, int n_in,
                              void* d_out, int out_size, void* d_ws, size_t ws_size,
                              hipStream_t stream)
{
    const float* x     = (const float*)d_in[0];
    const int*   ei    = (const int*)d_in[1];   // [2,E]: src = ei[0..E), dst = ei[E..2E)
    const float* W     = (const float*)d_in[2];
    const float* a_src = (const float*)d_in[3];
    const float* a_dst = (const float*)d_in[4];
    float* out = (float*)d_out;

    // Workspace layout (4B elems):
    // Wh[N*64] | s_src[N] | s_dst[N] | counts[N] | offsets[N+1] | cursor[N] |
    // csr_src[E] | csr_ev[E]   ->  ~21.6 MB
    float* ws      = (float*)d_ws;
    float* Wh      = ws;
    float* s_src   = Wh + (size_t)NN * FOUT;
    float* s_dst   = s_src + NN;
    int*   counts  = (int*)(s_dst + NN);
    int*   offsets = counts + NN;
    int*   cursor  = offsets + (NN + 1);
    int*   csr_src = cursor + NN;
    float* csr_ev  = (float*)(csr_src + NE);

    hipMemsetAsync(counts, 0, NN * sizeof(int), stream);

    k_gemm<<<1024, 256, 0, stream>>>(x, W, a_src, a_dst, Wh, s_src, s_dst);
    k_hist<<<(NE + 255) / 256, 256, 0, stream>>>(ei, counts);
    k_scan<<<1, 1024, 0, stream>>>(counts, offsets, cursor);
    k_fill<<<(NE + 255) / 256, 256, 0, stream>>>(ei, s_src, s_dst, cursor,
                                                 csr_src, csr_ev);
    k_gather<<<NN / 4, 256, 0, stream>>>(offsets, csr_src, csr_ev, Wh, out);
}